// Round 10
// baseline (176.609 us; speedup 1.0000x reference)
//
#include <hip/hip_runtime.h>
#include <hip/hip_fp16.h>

#define B_  64
#define L_  512
#define D_  768
#define S_  64
#define M_  4096
#define N1_ 384
#define N2_ 128

#define NBLK 256
#define NTHR 512

// ticket ranges (FIFO: weights, means, gemm1, gemm2)
#define T_W2   288                 // W1 tiles: [0,288)
#define T_MEAN 336                 // W2 tiles: [288,336)
#define T_G1   (T_MEAN + 1024)     // mean units: [336,1360), 16 per sample
#define T_G2   (T_G1 + 384)        // gemm1 tiles: [1360,1744), 6 per sample
#define T_END  (T_G2 + 64)         // gemm2 tiles: [1744,1808), 1 per sample

typedef __attribute__((ext_vector_type(8))) _Float16 half8;
typedef __attribute__((ext_vector_type(4))) float f32x4;

__device__ __forceinline__ ushort f2h(float x) {
  return __half_as_ushort(__float2half_rn(x));
}

// counters: q[0]=ticket q[1]=w1_done q[2]=w2_done q[3+b]=mean_cnt q[67+b]=g1_cnt
__global__ __launch_bounds__(NTHR, 2) void mega_kernel(
    const float* __restrict__ hidden, const int* __restrict__ seg_ids,
    const float* __restrict__ W1, const float* __restrict__ b1,
    const float* __restrict__ W2, const float* __restrict__ b2,
    const float* __restrict__ W3, const float* __restrict__ b3,
    ushort* __restrict__ mh, ushort* __restrict__ w1t,
    ushort* __restrict__ h1, ushort* __restrict__ w2t,
    unsigned int* __restrict__ q, float* __restrict__ out) {
  __shared__ __align__(16) char lds[31264];
  __shared__ int cur_t;
  const int tid = threadIdx.x;

  while (true) {
    __syncthreads();   // protects LDS reuse + orders prior ticket vs next claim
    if (tid == 0) cur_t = (int)atomicAdd(&q[0], 1u);
    __syncthreads();
    const int t = cur_t;
    if (t >= T_END) break;

    if (t < T_MEAN) {
      // ---------------- weight transpose tile (f16, B^T layout) ----------------
      const float* W; ushort* Wt; int K, N, nblk, kblk; unsigned int* sig;
      if (t < T_W2) { W = W1; Wt = w1t; K = D_;  N = N1_; nblk = t % 12; kblk = t / 12; sig = &q[1]; }
      else { int wb = t - T_W2; W = W2; Wt = w2t; K = N1_; N = N2_; nblk = wb % 4; kblk = wb / 4; sig = &q[2]; }
      float (*tile)[33] = (float(*)[33])lds;
      const int n0 = nblk * 32, k0 = kblk * 32;
      const int tx = tid & 31, ty = tid >> 5;
      if (tid < 192)
        for (int r = ty; r < 32; r += 6)
          tile[r][tx] = W[(size_t)(k0 + r) * N + n0 + tx];
      __syncthreads();
      if (tid < 192)
        for (int r = ty; r < 32; r += 6)
          Wt[(size_t)(n0 + r) * K + k0 + tx] = f2h(tile[tx][r]);
      __syncthreads();
      if (tid == 0) { __threadfence(); __hip_atomic_fetch_add(sig, 1u, __ATOMIC_RELEASE, __HIP_MEMORY_SCOPE_AGENT); }

    } else if (t < T_G1) {
      // ---------------- streaming segment-mean, 4 segments per ticket ----------------
      const int u  = t - T_MEAN;
      const int b  = u >> 4;
      const int s0 = (u & 15) * 4;
      int* sids = (int*)lds;               // 2048 B
      int* wred = (int*)(lds + 31232);     // 3 ints
      int pk = 0;
      if (tid < 128) {
        int4 v = ((const int4*)(seg_ids + b * L_))[tid];
        ((int4*)sids)[tid] = v;
        int clo = (v.x < s0) + (v.y < s0) + (v.z < s0) + (v.w < s0);
        int chi = (v.x < s0 + 4) + (v.y < s0 + 4) + (v.z < s0 + 4) + (v.w < s0 + 4);
        pk = clo * 1024 + chi;
      }
      #pragma unroll
      for (int off = 1; off < 64; off <<= 1) pk += __shfl_xor(pk, off);
      if (tid < 192 && (tid & 63) == 0) wred[tid >> 6] = pk;
      __syncthreads();
      if (tid < 192) {
        const int tot = wred[0] + wred[1] + wred[2];
        const int lo = tot >> 10;
        const int hi = tot & 1023;
        const float4* hp = (const float4*)(hidden + (size_t)b * L_ * D_) + tid;
        ushort* outb = mh + (size_t)b * S_ * D_ + tid * 4;
        const uint2 zz = {0u, 0u};
        int cur = (lo < hi) ? sids[lo] : s0 + 4;
        for (int z = s0; z < cur; ++z)
          *(uint2*)(outb + (size_t)z * D_) = zz;
        float4 acc = {0.0f, 0.0f, 0.0f, 0.0f};
        int segstart = lo;
        for (int l = lo; l < hi; l += 8) {
          float4 v[8]; int sv[8];
          #pragma unroll
          for (int k = 0; k < 8; ++k) {
            v[k]  = hp[(size_t)min(l + k, hi - 1) * (D_ / 4)];
            sv[k] = sids[min(l + k + 1, hi - 1)];
          }
          #pragma unroll
          for (int k = 0; k < 8; ++k) {
            if (l + k < hi) {
              acc.x += v[k].x; acc.y += v[k].y;
              acc.z += v[k].z; acc.w += v[k].w;
              const int nx = l + k + 1;
              if (nx == hi || sv[k] != cur) {
                const float inv = 1.0f / (float)(nx - segstart);
                ushort4 h;
                h.x = f2h(acc.x * inv); h.y = f2h(acc.y * inv);
                h.z = f2h(acc.z * inv); h.w = f2h(acc.w * inv);
                *(ushort4*)(outb + (size_t)cur * D_) = h;
                const int nxt = (nx == hi) ? s0 + 4 : sv[k];
                for (int z = cur + 1; z < nxt; ++z)
                  *(uint2*)(outb + (size_t)z * D_) = zz;
                acc.x = 0.0f; acc.y = 0.0f; acc.z = 0.0f; acc.w = 0.0f;
                segstart = nx; cur = nxt;
              }
            }
          }
        }
      }
      __syncthreads();
      if (tid == 0) { __threadfence(); __hip_atomic_fetch_add(&q[3 + b], 1u, __ATOMIC_RELEASE, __HIP_MEMORY_SCOPE_AGENT); }

    } else if (t < T_G2) {
      // ---------------- gemm1 tile: 64x64 of h1 = relu(means @ W1 + b1) ----------------
      const int u = t - T_G1;
      const int b = u / 6, nt = u % 6;
      if (tid == 0) {
        while (__hip_atomic_load(&q[1], __ATOMIC_ACQUIRE, __HIP_MEMORY_SCOPE_AGENT) < 288u)
          __builtin_amdgcn_s_sleep(8);
        while (__hip_atomic_load(&q[3 + b], __ATOMIC_ACQUIRE, __HIP_MEMORY_SCOPE_AGENT) < 16u)
          __builtin_amdgcn_s_sleep(8);
        __threadfence();
      }
      __syncthreads();

      constexpr int LDK = 72;
      ushort* sA = (ushort*)lds;
      ushort* sB = (ushort*)lds + 64 * LDK;
      const int wid = tid >> 6, lane = tid & 63;
      const int w2v = wid & 3, kh = (wid >> 2) * 32;
      const int m0 = (w2v >> 1) * 32, n0g = (w2v & 1) * 32;
      const int lrow = lane & 15, lk = (lane >> 4) * 8;
      const int hf = tid >> 8, t8 = tid & 255;
      const int srow = t8 >> 2, sk = (t8 & 3) * 16;
      const int soff = srow * LDK + sk;
      const int brow = b * 64, bcol = nt * 64;
      const ushort* gp = hf ? (w1t + (size_t)(bcol + srow) * D_ + sk)
                            : (mh + (size_t)(brow + srow) * D_ + sk);
      ushort* sp = hf ? sB : sA;

      uint4 r0 = *(const uint4*)gp;
      uint4 r1 = *(const uint4*)(gp + 8);
      f32x4 acc[2][2] = {};
      #pragma unroll 1
      for (int kt = 0; kt < 12; ++kt) {
        *(uint4*)&sp[soff]     = r0;
        *(uint4*)&sp[soff + 8] = r1;
        __syncthreads();
        if (kt + 1 < 12) {
          r0 = *(const uint4*)(gp + (size_t)(kt + 1) * 64);
          r1 = *(const uint4*)(gp + (size_t)(kt + 1) * 64 + 8);
        }
        half8 av[2], bv[2];
        #pragma unroll
        for (int i = 0; i < 2; ++i) {
          av[i] = *(const half8*)&sA[(m0 + i * 16 + lrow) * LDK + kh + lk];
          bv[i] = *(const half8*)&sB[(n0g + i * 16 + lrow) * LDK + kh + lk];
        }
        #pragma unroll
        for (int i = 0; i < 2; ++i)
          #pragma unroll
          for (int j = 0; j < 2; ++j)
            acc[i][j] = __builtin_amdgcn_mfma_f32_16x16x32_f16(av[i], bv[j], acc[i][j], 0, 0, 0);
        __syncthreads();
      }
      // combine K-split halves through LDS
      float* red = (float*)lds;
      const int roff = (w2v * 64 + lane) * 18;
      if (wid >= 4) {
        #pragma unroll
        for (int i = 0; i < 2; ++i)
          #pragma unroll
          for (int j = 0; j < 2; ++j) {
            *(float2*)&red[roff + i * 8 + j * 4]     = make_float2(acc[i][j][0], acc[i][j][1]);
            *(float2*)&red[roff + i * 8 + j * 4 + 2] = make_float2(acc[i][j][2], acc[i][j][3]);
          }
      }
      __syncthreads();
      if (wid < 4) {
        #pragma unroll
        for (int i = 0; i < 2; ++i)
          #pragma unroll
          for (int j = 0; j < 2; ++j) {
            float2 p0 = *(float2*)&red[roff + i * 8 + j * 4];
            float2 p1 = *(float2*)&red[roff + i * 8 + j * 4 + 2];
            acc[i][j][0] += p0.x; acc[i][j][1] += p0.y;
            acc[i][j][2] += p1.x; acc[i][j][3] += p1.y;
            const float bj = b1[bcol + n0g + j * 16 + lrow];
            #pragma unroll
            for (int r = 0; r < 4; ++r) {
              float v = fmaxf(acc[i][j][r] + bj, 0.0f);
              h1[(size_t)(brow + m0 + i * 16 + (lane >> 4) * 4 + r) * N1_ +
                 bcol + n0g + j * 16 + lrow] = f2h(v);
            }
          }
      }
      __syncthreads();
      if (tid == 0) { __threadfence(); __hip_atomic_fetch_add(&q[67 + b], 1u, __ATOMIC_RELEASE, __HIP_MEMORY_SCOPE_AGENT); }

    } else {
      // ---------------- gemm2+final for one sample (64 rows), 8 waves ----------------
      const int b = t - T_G2;
      if (tid == 0) {
        while (__hip_atomic_load(&q[2], __ATOMIC_ACQUIRE, __HIP_MEMORY_SCOPE_AGENT) < 48u)
          __builtin_amdgcn_s_sleep(8);
        while (__hip_atomic_load(&q[67 + b], __ATOMIC_ACQUIRE, __HIP_MEMORY_SCOPE_AGENT) < 6u)
          __builtin_amdgcn_s_sleep(8);
        __threadfence();
      }
      __syncthreads();

      constexpr int LDA2 = 40;
      ushort* sA2 = (ushort*)lds;                  // [2][64*40]
      ushort* sB2 = (ushort*)(lds + 10240);        // [2][128*40]
      float*  pl  = (float*)(lds + 30720);         // [64][2] flat 128 floats
      const int wid = tid >> 6, lane = tid & 63;
      const int hw = wid >> 2;                     // row half: 0 or 1
      const int n0 = (wid & 3) * 32;
      const int rbase = hw * 32;
      const int lrow = lane & 15, lk = (lane >> 4) * 8;
      const int brow = b * 64;

      const ushort* pA = nullptr; const ushort* pB = nullptr;
      int offA = 0, offB = 0;
      if (tid < 256) {
        const int srA = tid >> 2, skA = (tid & 3) * 8;
        pA = h1 + (size_t)(brow + srA) * N1_ + skA;
        offA = srA * LDA2 + skA;
      } else {
        const int t8 = tid - 256;
        const int srB = t8 >> 1, skB = (t8 & 1) * 16;
        pB = w2t + (size_t)srB * N1_ + skB;
        offB = srB * LDA2 + skB;
      }
      uint4 ra = {0,0,0,0}, rb0 = {0,0,0,0}, rb1 = {0,0,0,0};
      if (tid < 256) ra = *(const uint4*)pA;
      else { rb0 = *(const uint4*)pB; rb1 = *(const uint4*)(pB + 8); }
      if (tid < 256) *(uint4*)&sA2[offA] = ra;
      else { *(uint4*)&sB2[offB] = rb0; *(uint4*)&sB2[offB + 8] = rb1; }
      __syncthreads();

      f32x4 acc[2][2] = {};
      #pragma unroll 1
      for (int kt = 0; kt < 12; ++kt) {
        const int cur = kt & 1;
        if (kt + 1 < 12) {
          if (tid < 256) ra = *(const uint4*)(pA + (size_t)(kt + 1) * 32);
          else {
            rb0 = *(const uint4*)(pB + (size_t)(kt + 1) * 32);
            rb1 = *(const uint4*)(pB + (size_t)(kt + 1) * 32 + 8);
          }
        }
        half8 av[2], bv[2];
        #pragma unroll
        for (int i = 0; i < 2; ++i)
          av[i] = *(const half8*)&sA2[cur * 2560 + (rbase + i * 16 + lrow) * LDA2 + lk];
        #pragma unroll
        for (int j = 0; j < 2; ++j)
          bv[j] = *(const half8*)&sB2[cur * 5120 + (n0 + j * 16 + lrow) * LDA2 + lk];
        #pragma unroll
        for (int i = 0; i < 2; ++i)
          #pragma unroll
          for (int j = 0; j < 2; ++j)
            acc[i][j] = __builtin_amdgcn_mfma_f32_16x16x32_f16(av[i], bv[j], acc[i][j], 0, 0, 0);
        if (kt + 1 < 12) {
          __syncthreads();
          const int nxt = cur ^ 1;
          if (tid < 256) *(uint4*)&sA2[nxt * 2560 + offA] = ra;
          else { *(uint4*)&sB2[nxt * 5120 + offB] = rb0; *(uint4*)&sB2[nxt * 5120 + offB + 8] = rb1; }
          __syncthreads();
        }
      }

      __syncthreads();
      if (tid < 128) pl[tid] = 0.0f;
      float w3v[2][2], b2v[2];
      #pragma unroll
      for (int j = 0; j < 2; ++j) {
        const int col = n0 + j * 16 + lrow;
        w3v[j][0] = W3[col * 2 + 0];
        w3v[j][1] = W3[col * 2 + 1];
        b2v[j] = b2[col];
      }
      __syncthreads();
      #pragma unroll
      for (int i = 0; i < 2; ++i)
        #pragma unroll
        for (int r = 0; r < 4; ++r) {
          float p0 = 0.0f, p1 = 0.0f;
          #pragma unroll
          for (int j = 0; j < 2; ++j) {
            float v = fmaxf(acc[i][j][r] + b2v[j], 0.0f);
            p0 += v * w3v[j][0];
            p1 += v * w3v[j][1];
          }
          p0 += __shfl_xor(p0, 1); p1 += __shfl_xor(p1, 1);
          p0 += __shfl_xor(p0, 2); p1 += __shfl_xor(p1, 2);
          p0 += __shfl_xor(p0, 4); p1 += __shfl_xor(p1, 4);
          p0 += __shfl_xor(p0, 8); p1 += __shfl_xor(p1, 8);
          if (lrow == 0) {
            const int row = rbase + i * 16 + (lane >> 4) * 4 + r;   // 0..63
            atomicAdd(&pl[row * 2 + 0], p0);
            atomicAdd(&pl[row * 2 + 1], p1);
          }
        }
      __syncthreads();
      if (tid < 128) {
        const int row = tid >> 1, c = tid & 1;
        out[(size_t)(brow + row) * 2 + c] = pl[tid] + b3[c];
      }
      // no signal: d_out is terminal
    }
  }
}

// ---------------------------------------------------------------------------
extern "C" void kernel_launch(void* const* d_in, const int* in_sizes, int n_in,
                              void* d_out, int out_size, void* d_ws, size_t ws_size,
                              hipStream_t stream) {
  const float* hidden  = (const float*)d_in[0];
  const int*   seg_ids = (const int*)d_in[1];
  const float* W1 = (const float*)d_in[2];
  const float* b1 = (const float*)d_in[3];
  const float* W2 = (const float*)d_in[4];
  const float* b2 = (const float*)d_in[5];
  const float* W3 = (const float*)d_in[6];
  const float* b3 = (const float*)d_in[7];
  float* out = (float*)d_out;

  char* p = (char*)d_ws;
  ushort* mh  = (ushort*)p;  p += (size_t)M_ * D_ * 2;     // means f16
  ushort* w1t = (ushort*)p;  p += (size_t)N1_ * D_ * 2;    // W1^T f16
  ushort* h1  = (ushort*)p;  p += (size_t)M_ * N1_ * 2;    // h1 f16
  ushort* w2t = (ushort*)p;  p += (size_t)N2_ * N1_ * 2;   // W2^T f16
  unsigned int* q = (unsigned int*)p;                      // 131 counters

  hipMemsetAsync(q, 0, 131 * sizeof(unsigned int), stream);
  mega_kernel<<<NBLK, NTHR, 0, stream>>>(
      hidden, seg_ids, W1, b1, W2, b2, W3, b3, mh, w1t, h1, w2t, q, out);
}

// Round 11
// 58.993 us; speedup vs baseline: 2.9937x; 2.9937x over previous
//
#include <hip/hip_runtime.h>
#include <hip/hip_fp16.h>

#define B_  64
#define L_  512
#define D_  768
#define S_  64
#define M_  4096
#define N1_ 384
#define N2_ 128
#define SEG_C 4               // segments per mean block
#define NMB (M_ / SEG_C)      // 1024 mean blocks

typedef __attribute__((ext_vector_type(8))) _Float16 half8;
typedef __attribute__((ext_vector_type(4))) float f32x4;

__device__ __forceinline__ ushort f2h(float x) {
  return __half_as_ushort(__float2half_rn(x));
}

// ---------------------------------------------------------------------------
// Kernel 1 (one launch):
//  blocks 0..1023: streaming segment-mean over a (sample, 4-segment) chunk.
//  blocks 1024.. : weight transpose to B^T layout, single f16.
// NOTE R11: launched TWICE as a timing probe (idempotent overwrite) —
// delta vs R9's 41.0 us isolates one warm mean_prep pass.
// ---------------------------------------------------------------------------
__global__ __launch_bounds__(192) void mean_prep_kernel(
    const float* __restrict__ hidden, const int* __restrict__ seg_ids,
    ushort* __restrict__ mh,
    const float* __restrict__ W1, ushort* __restrict__ w1t,
    const float* __restrict__ W2, ushort* __restrict__ w2t) {
  const int bid = blockIdx.x;
  const int tid = threadIdx.x;

  if (bid < NMB) {
    const int b  = bid >> 4;
    const int s0 = (bid & 15) * SEG_C;
    __shared__ int sids[L_];
    __shared__ int wred[3];
    int pk = 0;
    if (tid < 128) {
      int4 v = ((const int4*)(seg_ids + b * L_))[tid];
      ((int4*)sids)[tid] = v;
      int clo = (v.x < s0) + (v.y < s0) + (v.z < s0) + (v.w < s0);
      int chi = (v.x < s0 + SEG_C) + (v.y < s0 + SEG_C) +
                (v.z < s0 + SEG_C) + (v.w < s0 + SEG_C);
      pk = clo * 1024 + chi;   // both <= 512: no carry between fields
    }
    #pragma unroll
    for (int off = 1; off < 64; off <<= 1) pk += __shfl_xor(pk, off);
    if ((tid & 63) == 0) wred[tid >> 6] = pk;
    __syncthreads();
    const int tot = wred[0] + wred[1] + wred[2];
    const int lo = tot >> 10;
    const int hi = tot & 1023;

    const float4* hp = (const float4*)(hidden + (size_t)b * L_ * D_) + tid;
    ushort* outb = mh + (size_t)b * S_ * D_ + tid * 4;  // row stride D_
    const uint2 zz = {0u, 0u};

    int cur = (lo < hi) ? sids[lo] : s0 + SEG_C;
    for (int z = s0; z < cur; ++z)          // leading empty segments
      *(uint2*)(outb + (size_t)z * D_) = zz;

    float4 acc = {0.0f, 0.0f, 0.0f, 0.0f};
    int segstart = lo;
    for (int l = lo; l < hi; l += 8) {
      float4 v[8];
      int sv[8];
      #pragma unroll
      for (int k = 0; k < 8; ++k) {
        v[k]  = hp[(size_t)min(l + k, hi - 1) * (D_ / 4)];
        sv[k] = sids[min(l + k + 1, hi - 1)];
      }
      #pragma unroll
      for (int k = 0; k < 8; ++k) {
        if (l + k < hi) {      // uniform
          acc.x += v[k].x; acc.y += v[k].y;
          acc.z += v[k].z; acc.w += v[k].w;
          const int nx = l + k + 1;
          if (nx == hi || sv[k] != cur) {   // uniform flush
            const float inv = 1.0f / (float)(nx - segstart);
            ushort4 h;
            h.x = f2h(acc.x * inv); h.y = f2h(acc.y * inv);
            h.z = f2h(acc.z * inv); h.w = f2h(acc.w * inv);
            *(ushort4*)(outb + (size_t)cur * D_) = h;
            const int nxt = (nx == hi) ? s0 + SEG_C : sv[k];
            for (int z = cur + 1; z < nxt; ++z)   // interior/trailing empties
              *(uint2*)(outb + (size_t)z * D_) = zz;
            acc.x = 0.0f; acc.y = 0.0f; acc.z = 0.0f; acc.w = 0.0f;
            segstart = nx; cur = nxt;
          }
        }
      }
    }
  } else {
    // ---- weight transpose, single f16 (32x32 tiles, 192 threads) ----
    int wb = bid - NMB;
    const float* W; ushort* Wt; int K, N, nblk, kblk;
    if (wb < 288) {  // W1: 12 col-tiles x 24 row-tiles
      W = W1; Wt = w1t; K = D_; N = N1_;
      nblk = wb % 12; kblk = wb / 12;
    } else {         // W2: 4 x 12
      wb -= 288;
      W = W2; Wt = w2t; K = N1_; N = N2_;
      nblk = wb % 4; kblk = wb / 4;
    }
    __shared__ float tile[32][33];
    const int n0 = nblk * 32, k0 = kblk * 32;
    const int tx = tid & 31, ty = tid >> 5;  // 32 x 6
    for (int r = ty; r < 32; r += 6)
      tile[r][tx] = W[(size_t)(k0 + r) * N + n0 + tx];
    __syncthreads();
    for (int r = ty; r < 32; r += 6)
      Wt[(size_t)(n0 + r) * K + k0 + tx] = f2h(tile[tx][r]);
  }
}

// ---------------------------------------------------------------------------
// Kernel 2: GEMM1 via MFMA f16 single-pass, 8 waves with K-split.
// ---------------------------------------------------------------------------
__global__ __launch_bounds__(512) void gemm_mfma8(
    const ushort* __restrict__ As, const ushort* __restrict__ Bs,
    const float* __restrict__ bias, ushort* __restrict__ Cs,
    int M, int N, int K) {
  constexpr int LDK = 72;  // 64 + 8 pad: frag-read rows 2-way alias only
  __shared__ __align__(16) ushort smem[2 * 64 * LDK];  // 18,432 B
  ushort* sA = smem;
  ushort* sB = smem + 64 * LDK;

  const int tid  = threadIdx.x;
  const int wid  = tid >> 6;
  const int lane = tid & 63;
  const int w2 = wid & 3;
  const int kh = (wid >> 2) * 32;       // K-split: 0 or 32 within BK=64
  const int m0 = (w2 >> 1) * 32;
  const int n0 = (w2 & 1) * 32;
  const int lrow = lane & 15;
  const int lk   = (lane >> 4) * 8;

  const int half = tid >> 8;            // 0: A, 1: B
  const int t8   = tid & 255;
  const int srow = t8 >> 2;             // 0..63
  const int sk   = (t8 & 3) * 16;       // 0,16,32,48
  const int soff = srow * LDK + sk;

  const int brow = blockIdx.y * 64;
  const int bcol = blockIdx.x * 64;

  const ushort* gp = half ? (Bs + (size_t)(bcol + srow) * K + sk)
                          : (As + (size_t)(brow + srow) * K + sk);
  ushort* sp = half ? sB : sA;

  const int NT = K / 64;   // 12 for K=768

  uint4 r0 = *(const uint4*)gp;
  uint4 r1 = *(const uint4*)(gp + 8);

  f32x4 acc[2][2] = {};

  for (int t = 0; t < NT; ++t) {
    *(uint4*)&sp[soff]     = r0;
    *(uint4*)&sp[soff + 8] = r1;
    __syncthreads();
    if (t + 1 < NT) {
      r0 = *(const uint4*)(gp + (size_t)(t + 1) * 64);
      r1 = *(const uint4*)(gp + (size_t)(t + 1) * 64 + 8);
    }
    half8 av[2], bv[2];
    #pragma unroll
    for (int i = 0; i < 2; ++i) {
      av[i] = *(const half8*)&sA[(m0 + i * 16 + lrow) * LDK + kh + lk];
      bv[i] = *(const half8*)&sB[(n0 + i * 16 + lrow) * LDK + kh + lk];
    }
    #pragma unroll
    for (int i = 0; i < 2; ++i)
      #pragma unroll
      for (int j = 0; j < 2; ++j)
        acc[i][j] = __builtin_amdgcn_mfma_f32_16x16x32_f16(av[i], bv[j], acc[i][j], 0, 0, 0);
    __syncthreads();
  }

  // ---- combine K-split partials through LDS (stride 18 dwords: 2-way) ----
  float* red = (float*)smem;
  const int roff = (w2 * 64 + lane) * 18;
  if (wid >= 4) {
    #pragma unroll
    for (int i = 0; i < 2; ++i)
      #pragma unroll
      for (int j = 0; j < 2; ++j) {
        *(float2*)&red[roff + i * 8 + j * 4]     = make_float2(acc[i][j][0], acc[i][j][1]);
        *(float2*)&red[roff + i * 8 + j * 4 + 2] = make_float2(acc[i][j][2], acc[i][j][3]);
      }
  }
  __syncthreads();
  if (wid < 4) {
    #pragma unroll
    for (int i = 0; i < 2; ++i)
      #pragma unroll
      for (int j = 0; j < 2; ++j) {
        float2 p0 = *(float2*)&red[roff + i * 8 + j * 4];
        float2 p1 = *(float2*)&red[roff + i * 8 + j * 4 + 2];
        acc[i][j][0] += p0.x; acc[i][j][1] += p0.y;
        acc[i][j][2] += p1.x; acc[i][j][3] += p1.y;
        const float bj = bias[bcol + n0 + j * 16 + lrow];
        #pragma unroll
        for (int r = 0; r < 4; ++r) {
          float v = fmaxf(acc[i][j][r] + bj, 0.0f);
          const size_t idx =
              (size_t)(brow + m0 + i * 16 + (lane >> 4) * 4 + r) * N +
              bcol + n0 + j * 16 + lrow;
          Cs[idx] = f2h(v);
        }
      }
  }
}

// ---------------------------------------------------------------------------
// Kernel 3: GEMM2 (h1 @ W2 + b2, relu) fused with final (@ W3 + b3).
// ---------------------------------------------------------------------------
__global__ __launch_bounds__(256) void gemm2_final(
    const ushort* __restrict__ As, const ushort* __restrict__ Bs,
    const float* __restrict__ b2, const float* __restrict__ W3,
    const float* __restrict__ b3, float* __restrict__ out) {
  constexpr int K = N1_;   // 384
  constexpr int LDA = 40;
  __shared__ __align__(16) ushort sA[2][32 * LDA];
  __shared__ __align__(16) ushort sB[2][128 * LDA];
  __shared__ float pl[32][2];

  const int tid  = threadIdx.x;
  const int wid  = tid >> 6;
  const int lane = tid & 63;
  const int n0 = wid * 32;          // wave's 32-col slice of N2=128
  const int lrow = lane & 15;
  const int lk   = (lane >> 4) * 8;
  const int brow = blockIdx.x * 32;

  const int t7  = tid & 127;
  const int srA = t7 >> 2, skA = (t7 & 3) * 8;
  const ushort* pA = As + (size_t)(brow + srA) * K + skA;
  const int offA = srA * LDA + skA;
  const int srB = tid >> 1, skB = (tid & 1) * 16;
  const ushort* pB = Bs + (size_t)srB * K + skB;
  const int offB = srB * LDA + skB;

  uint4 ra = {0, 0, 0, 0};
  if (tid < 128) ra = *(const uint4*)pA;
  uint4 rb0 = *(const uint4*)pB;
  uint4 rb1 = *(const uint4*)(pB + 8);
  if (tid < 128) *(uint4*)&sA[0][offA] = ra;
  *(uint4*)&sB[0][offB] = rb0;
  *(uint4*)&sB[0][offB + 8] = rb1;
  __syncthreads();

  f32x4 acc[2][2] = {};
  constexpr int NT = K / 32;  // 12

  for (int t = 0; t < NT; ++t) {
    const int cur = t & 1;
    if (t + 1 < NT) {
      if (tid < 128) ra = *(const uint4*)(pA + (size_t)(t + 1) * 32);
      rb0 = *(const uint4*)(pB + (size_t)(t + 1) * 32);
      rb1 = *(const uint4*)(pB + (size_t)(t + 1) * 32 + 8);
    }
    half8 av[2], bv[2];
    #pragma unroll
    for (int i = 0; i < 2; ++i)
      av[i] = *(const half8*)&sA[cur][(i * 16 + lrow) * LDA + lk];
    #pragma unroll
    for (int j = 0; j < 2; ++j)
      bv[j] = *(const half8*)&sB[cur][(n0 + j * 16 + lrow) * LDA + lk];
    #pragma unroll
    for (int i = 0; i < 2; ++i)
      #pragma unroll
      for (int j = 0; j < 2; ++j)
        acc[i][j] = __builtin_amdgcn_mfma_f32_16x16x32_f16(av[i], bv[j], acc[i][j], 0, 0, 0);
    if (t + 1 < NT) {
      __syncthreads();
      const int nxt = cur ^ 1;
      if (tid < 128) *(uint4*)&sA[nxt][offA] = ra;
      *(uint4*)&sB[nxt][offB] = rb0;
      *(uint4*)&sB[nxt][offB + 8] = rb1;
      __syncthreads();
    }
  }

  __syncthreads();
  if (tid < 64) pl[tid >> 1][tid & 1] = 0.0f;
  float w3v[2][2], b2v[2];
  #pragma unroll
  for (int j = 0; j < 2; ++j) {
    const int col = n0 + j * 16 + lrow;
    w3v[j][0] = W3[col * 2 + 0];
    w3v[j][1] = W3[col * 2 + 1];
    b2v[j] = b2[col];
  }
  __syncthreads();
  #pragma unroll
  for (int i = 0; i < 2; ++i)
    #pragma unroll
    for (int r = 0; r < 4; ++r) {
      float p0 = 0.0f, p1 = 0.0f;
      #pragma unroll
      for (int j = 0; j < 2; ++j) {
        float v = fmaxf(acc[i][j][r] + b2v[j], 0.0f);
        p0 += v * w3v[j][0];
        p1 += v * w3v[j][1];
      }
      p0 += __shfl_xor(p0, 1); p1 += __shfl_xor(p1, 1);
      p0 += __shfl_xor(p0, 2); p1 += __shfl_xor(p1, 2);
      p0 += __shfl_xor(p0, 4); p1 += __shfl_xor(p1, 4);
      p0 += __shfl_xor(p0, 8); p1 += __shfl_xor(p1, 8);
      if (lrow == 0) {
        const int row = i * 16 + (lane >> 4) * 4 + r;
        atomicAdd(&pl[row][0], p0);
        atomicAdd(&pl[row][1], p1);
      }
    }
  __syncthreads();
  if (tid < 64) {
    const int row = tid >> 1, c = tid & 1;
    out[(size_t)(brow + row) * 2 + c] = pl[row][c] + b3[c];
  }
}

// ---------------------------------------------------------------------------
extern "C" void kernel_launch(void* const* d_in, const int* in_sizes, int n_in,
                              void* d_out, int out_size, void* d_ws, size_t ws_size,
                              hipStream_t stream) {
  const float* hidden  = (const float*)d_in[0];
  const int*   seg_ids = (const int*)d_in[1];
  const float* W1 = (const float*)d_in[2];
  const float* b1 = (const float*)d_in[3];
  const float* W2 = (const float*)d_in[4];
  const float* b2 = (const float*)d_in[5];
  const float* W3 = (const float*)d_in[6];
  const float* b3 = (const float*)d_in[7];
  float* out = (float*)d_out;

  char* p = (char*)d_ws;
  ushort* mh  = (ushort*)p;  p += (size_t)M_ * D_ * 2;     // means f16
  ushort* w1t = (ushort*)p;  p += (size_t)N1_ * D_ * 2;    // W1^T f16
  ushort* h1  = (ushort*)p;  p += (size_t)M_ * N1_ * 2;    // h1 f16
  ushort* w2t = (ushort*)p;  p += (size_t)N2_ * N1_ * 2;   // W2^T f16

  // R11 probe: mean_prep launched twice (idempotent). Delta vs R9 total
  // isolates one warm mean_prep pass.
  mean_prep_kernel<<<NMB + 288 + 48, 192, 0, stream>>>(
      hidden, seg_ids, mh, W1, w1t, W2, w2t);
  mean_prep_kernel<<<NMB + 288 + 48, 192, 0, stream>>>(
      hidden, seg_ids, mh, W1, w1t, W2, w2t);
  gemm_mfma8<<<dim3(N1_ / 64, M_ / 64), 512, 0, stream>>>(
      mh, w1t, b1, h1, M_, N1_, D_);
  gemm2_final<<<M_ / 32, 256, 0, stream>>>(
      h1, w2t, b2, W3, b3, out);
}